// Round 1
// baseline (2743.649 us; speedup 1.0000x reference)
//
#include <hip/hip_runtime.h>

#define NROWS 4096
#define FOUT 256
#define NHEADS 4
#define DHEAD 64
#define QKV_LD 768
#define TR 16
#define TJ 32
#define NEGINF_MASK -9.0e15f
#define LRELU_ALPHA 0.2f
#define ATTN_SCALE 0.0625f

__device__ __forceinline__ float warp16_max(float v) {
#pragma unroll
    for (int off = 8; off; off >>= 1) v = fmaxf(v, __shfl_xor(v, off, 16));
    return v;
}
__device__ __forceinline__ float warp16_sum(float v) {
#pragma unroll
    for (int off = 8; off; off >>= 1) v += __shfl_xor(v, off, 16);
    return v;
}

// ---------------------------------------------------------------------------
// Tiled fp32 GEMM: C[M][Nn] = A[M][K] @ B' (+bias), B' = BT ? B[Nn][K]^T : B[K][Nn]
// BM=BN=64, BK=16, 256 threads, 4x4 micro-tile per thread.
// ---------------------------------------------------------------------------
template <bool BT, bool BIAS>
__global__ __launch_bounds__(256) void gemm_f32(
    const float* __restrict__ A, const float* __restrict__ B,
    const float* __restrict__ bias, float* __restrict__ C,
    int M, int Nn, int K)
{
    __shared__ float As[16][68];
    __shared__ float Bs[16][68];

    const int tid = threadIdx.x;
    const int bm = blockIdx.y * 64;
    const int bn = blockIdx.x * 64;
    const int tx = tid & 15;
    const int ty = tid >> 4;

    float acc[4][4];
#pragma unroll
    for (int r = 0; r < 4; ++r)
#pragma unroll
        for (int c = 0; c < 4; ++c) acc[r][c] = 0.0f;

    for (int k0 = 0; k0 < K; k0 += 16) {
        __syncthreads();
        {   // A tile: 64 rows x 16 k, transposed into As[k][m]
            const int r = tid >> 2;
            const int c4 = (tid & 3) * 4;
            float4 a4 = *(const float4*)&A[(size_t)(bm + r) * K + k0 + c4];
            As[c4 + 0][r] = a4.x; As[c4 + 1][r] = a4.y;
            As[c4 + 2][r] = a4.z; As[c4 + 3][r] = a4.w;
        }
        if (!BT) {  // B[k][n] -> Bs[k][n]
            const int r = tid >> 4;
            const int c4 = (tid & 15) * 4;
            *(float4*)&Bs[r][c4] = *(const float4*)&B[(size_t)(k0 + r) * Nn + bn + c4];
        } else {    // B[n][k] -> Bs[k][n]
            const int r = tid >> 2;
            const int c4 = (tid & 3) * 4;
            float4 b4 = *(const float4*)&B[(size_t)(bn + r) * K + k0 + c4];
            Bs[c4 + 0][r] = b4.x; Bs[c4 + 1][r] = b4.y;
            Bs[c4 + 2][r] = b4.z; Bs[c4 + 3][r] = b4.w;
        }
        __syncthreads();
#pragma unroll
        for (int kk = 0; kk < 16; ++kk) {
            float4 a4 = *(const float4*)&As[kk][ty * 4];
            float4 b4 = *(const float4*)&Bs[kk][tx * 4];
            acc[0][0] += a4.x * b4.x; acc[0][1] += a4.x * b4.y; acc[0][2] += a4.x * b4.z; acc[0][3] += a4.x * b4.w;
            acc[1][0] += a4.y * b4.x; acc[1][1] += a4.y * b4.y; acc[1][2] += a4.y * b4.z; acc[1][3] += a4.y * b4.w;
            acc[2][0] += a4.z * b4.x; acc[2][1] += a4.z * b4.y; acc[2][2] += a4.z * b4.z; acc[2][3] += a4.z * b4.w;
            acc[3][0] += a4.w * b4.x; acc[3][1] += a4.w * b4.y; acc[3][2] += a4.w * b4.z; acc[3][3] += a4.w * b4.w;
        }
    }

    float bv[4] = {0.f, 0.f, 0.f, 0.f};
    if (BIAS) {
#pragma unroll
        for (int c = 0; c < 4; ++c) bv[c] = bias[bn + tx * 4 + c];
    }
#pragma unroll
    for (int r = 0; r < 4; ++r) {
        float4 o;
        o.x = acc[r][0] + bv[0]; o.y = acc[r][1] + bv[1];
        o.z = acc[r][2] + bv[2]; o.w = acc[r][3] + bv[3];
        *(float4*)&C[(size_t)(bm + ty * 4 + r) * Nn + bn + tx * 4] = o;
    }
}

// ---------------------------------------------------------------------------
// p1 = Wh @ a[:256], p2 = Wh @ a[256:]
// ---------------------------------------------------------------------------
__global__ __launch_bounds__(256) void compute_p(
    const float* __restrict__ Wh, const float* __restrict__ a,
    float* __restrict__ p1, float* __restrict__ p2)
{
    const int row = blockIdx.x * 16 + (threadIdx.x >> 4);
    const int c = threadIdx.x & 15;
    float s1 = 0.f, s2 = 0.f;
    for (int f = c; f < FOUT; f += 16) {
        float w = Wh[(size_t)row * FOUT + f];
        s1 += w * a[f];
        s2 += w * a[FOUT + f];
    }
    s1 = warp16_sum(s1);
    s2 = warp16_sum(s2);
    if (c == 0) { p1[row] = s1; p2[row] = s2; }
}

// ---------------------------------------------------------------------------
// Fused: per 16-row block — inner-attention stats (sweep 1), then
// dots/dsum/PV + outer masked flash softmax against Wh (sweep 2).
// ---------------------------------------------------------------------------
__global__ __launch_bounds__(256) void fused_graph_attn(
    const float* __restrict__ qkv,   // [N][768]  (q | k | v)
    const float* __restrict__ Wh,    // [N][256]
    const float* __restrict__ p1g,   // [N]
    const float* __restrict__ p2g,   // [N]
    const int* __restrict__ adj,     // [N][N]
    float* __restrict__ out)         // [N][256]
{
    __shared__ float q_lds[TR][FOUT + 4];
    __shared__ float k_lds[TJ][DHEAD + 4];
    __shared__ float dots_lds[TR][TJ + 4];
    __shared__ float ptil_lds[TR][TJ + 4];   // dsum during head loop, then p-tilde
    __shared__ float mz_lds[TR][NHEADS][2];  // m, 1/Z per (row, head)
    __shared__ float alpha_lds[TR];
    __shared__ float rowM_lds[TR];
    __shared__ float rowL_lds[TR];
    __shared__ float wh0_lds[TR][FOUT];

    const int tid = threadIdx.x;
    const int i0 = blockIdx.x * TR;
    const int sr = tid >> 4;          // score row 0..15
    const int sc = tid & 15;          // score col group 0..15

    // ---- load the block's q rows (all heads) into LDS ----
#pragma unroll
    for (int it = 0; it < 4; ++it) {
        int idx = tid + it * 256;         // 0..1023
        int r = idx >> 6;                 // 0..15
        int c4 = (idx & 63) << 2;         // 0..252
        *(float4*)&q_lds[r][c4] = *(const float4*)&qkv[(size_t)(i0 + r) * QKV_LD + c4];
    }

    // ================= sweep 1: per-head online softmax stats =================
    float m_h[NHEADS], z_h[NHEADS];
#pragma unroll
    for (int h = 0; h < NHEADS; ++h) { m_h[h] = -3.0e38f; z_h[h] = 0.0f; }

    for (int j0 = 0; j0 < NROWS; j0 += TJ) {
#pragma unroll
        for (int h = 0; h < NHEADS; ++h) {
            __syncthreads();
#pragma unroll
            for (int it = 0; it < 2; ++it) {
                int idx = tid + it * 256;
                int jj = idx >> 4;
                int d4 = (idx & 15) << 2;
                *(float4*)&k_lds[jj][d4] =
                    *(const float4*)&qkv[(size_t)(j0 + jj) * QKV_LD + FOUT + h * DHEAD + d4];
            }
            __syncthreads();
            float s0 = 0.f, s1 = 0.f;
#pragma unroll
            for (int d4 = 0; d4 < DHEAD; d4 += 4) {
                float4 q4 = *(const float4*)&q_lds[sr][h * DHEAD + d4];
                float4 ka = *(const float4*)&k_lds[sc][d4];
                float4 kb = *(const float4*)&k_lds[sc + 16][d4];
                s0 += q4.x * ka.x + q4.y * ka.y + q4.z * ka.z + q4.w * ka.w;
                s1 += q4.x * kb.x + q4.y * kb.y + q4.z * kb.z + q4.w * kb.w;
            }
            s0 *= ATTN_SCALE; s1 *= ATTN_SCALE;
            float mx = fmaxf(s0, s1);
            float nm = fmaxf(m_h[h], mx);
            z_h[h] = z_h[h] * __expf(m_h[h] - nm) + __expf(s0 - nm) + __expf(s1 - nm);
            m_h[h] = nm;
        }
    }
#pragma unroll
    for (int h = 0; h < NHEADS; ++h) {
        float m = m_h[h], z = z_h[h];
#pragma unroll
        for (int off = 8; off; off >>= 1) {
            float mo = __shfl_xor(m, off, 16);
            float zo = __shfl_xor(z, off, 16);
            float nm = fmaxf(m, mo);
            z = z * __expf(m - nm) + zo * __expf(mo - nm);
            m = nm;
        }
        if (sc == 0) { mz_lds[sr][h][0] = m; mz_lds[sr][h][1] = 1.0f / z; }
    }
    if (tid < TR) { rowM_lds[tid] = -3.0e38f; rowL_lds[tid] = 0.0f; }
    __syncthreads();

    // ================= sweep 2: dots, dsum, PV, outer flash softmax =================
    float wh0_acc[NHEADS][4];
#pragma unroll
    for (int h = 0; h < NHEADS; ++h)
#pragma unroll
        for (int c = 0; c < 4; ++c) wh0_acc[h][c] = 0.0f;
    float hp[4][4];
#pragma unroll
    for (int r = 0; r < 4; ++r)
#pragma unroll
        for (int c = 0; c < 4; ++c) hp[r][c] = 0.0f;

    const int prow = tid >> 4;            // PV row
    const int pc4 = (tid & 15) << 2;      // PV dim-in-head base
    const int hrow0 = (tid >> 6) << 2;    // hp rows base (wave-local rows)
    const int hc4 = (tid & 63) << 2;      // hp feature base
    const float p1v = p1g[i0 + sr];

    for (int j0 = 0; j0 < NROWS; j0 += TJ) {
#pragma unroll
        for (int h = 0; h < NHEADS; ++h) {
            __syncthreads();
#pragma unroll
            for (int it = 0; it < 2; ++it) {
                int idx = tid + it * 256;
                int jj = idx >> 4;
                int d4 = (idx & 15) << 2;
                *(float4*)&k_lds[jj][d4] =
                    *(const float4*)&qkv[(size_t)(j0 + jj) * QKV_LD + FOUT + h * DHEAD + d4];
            }
            __syncthreads();
            float s0 = 0.f, s1 = 0.f;
#pragma unroll
            for (int d4 = 0; d4 < DHEAD; d4 += 4) {
                float4 q4 = *(const float4*)&q_lds[sr][h * DHEAD + d4];
                float4 ka = *(const float4*)&k_lds[sc][d4];
                float4 kb = *(const float4*)&k_lds[sc + 16][d4];
                s0 += q4.x * ka.x + q4.y * ka.y + q4.z * ka.z + q4.w * ka.w;
                s1 += q4.x * kb.x + q4.y * kb.y + q4.z * kb.z + q4.w * kb.w;
            }
            s0 *= ATTN_SCALE; s1 *= ATTN_SCALE;
            const float mh = mz_lds[sr][h][0];
            const float iz = mz_lds[sr][h][1];
            float d0 = __expf(s0 - mh) * iz;
            float d1 = __expf(s1 - mh) * iz;
            dots_lds[sr][sc] = d0;
            dots_lds[sr][sc + 16] = d1;
            if (h == 0) {
                ptil_lds[sr][sc] = d0;
                ptil_lds[sr][sc + 16] = d1;
            } else {
                ptil_lds[sr][sc] += d0;
                ptil_lds[sr][sc + 16] += d1;
            }
            __syncthreads();
            // PV: Wh0[prow][h*64+pc4..+3] += sum_j dots * v
            {
                float a0 = wh0_acc[h][0], a1 = wh0_acc[h][1];
                float a2 = wh0_acc[h][2], a3 = wh0_acc[h][3];
                const float* vbase = &qkv[(size_t)j0 * QKV_LD + 2 * FOUT + h * DHEAD + pc4];
#pragma unroll 8
                for (int jj = 0; jj < TJ; ++jj) {
                    float p = dots_lds[prow][jj];
                    float4 v4 = *(const float4*)(vbase + (size_t)jj * QKV_LD);
                    a0 += p * v4.x; a1 += p * v4.y; a2 += p * v4.z; a3 += p * v4.w;
                }
                wh0_acc[h][0] = a0; wh0_acc[h][1] = a1;
                wh0_acc[h][2] = a2; wh0_acc[h][3] = a3;
            }
        }

        // ---- outer masked softmax, online, for this j tile ----
        {
            const int ja = j0 + sc, jb = ja + 16;
            const size_t arow = (size_t)(i0 + sr) * NROWS;
            float e0 = p1v + p2g[ja]; e0 = (e0 > 0.f) ? e0 : LRELU_ALPHA * e0;
            float e1 = p1v + p2g[jb]; e1 = (e1 > 0.f) ? e1 : LRELU_ALPHA * e1;
            float l0 = (adj[arow + ja] > 0) ? (e0 + ptil_lds[sr][sc]) : NEGINF_MASK;
            float l1 = (adj[arow + jb] > 0) ? (e1 + ptil_lds[sr][sc + 16]) : NEGINF_MASK;
            float tm = warp16_max(fmaxf(l0, l1));
            float Mold = rowM_lds[sr];  // same-wave lanes: read executes before the write below
            float Mnew = fmaxf(Mold, tm);
            float p0 = __expf(l0 - Mnew);
            float p1e = __expf(l1 - Mnew);
            float ps = warp16_sum(p0 + p1e);
            if (sc == 0) {
                float al = __expf(Mold - Mnew);
                rowM_lds[sr] = Mnew;
                rowL_lds[sr] = rowL_lds[sr] * al + ps;
                alpha_lds[sr] = al;
            }
            ptil_lds[sr][sc] = p0;
            ptil_lds[sr][sc + 16] = p1e;
        }
        __syncthreads();

        // ---- hp accumulate: hp[r][c] = sum_j ptil * Wh[j][hc4+c], flash-rescaled ----
        {
#pragma unroll
            for (int r = 0; r < 4; ++r) {
                float al = alpha_lds[hrow0 + r];
                hp[r][0] *= al; hp[r][1] *= al; hp[r][2] *= al; hp[r][3] *= al;
            }
            const float* wbase = &Wh[(size_t)j0 * FOUT + hc4];
#pragma unroll 4
            for (int jj = 0; jj < TJ; ++jj) {
                float4 w4 = *(const float4*)(wbase + (size_t)jj * FOUT);
#pragma unroll
                for (int r = 0; r < 4; ++r) {
                    float p = ptil_lds[hrow0 + r][jj];
                    hp[r][0] += p * w4.x; hp[r][1] += p * w4.y;
                    hp[r][2] += p * w4.z; hp[r][3] += p * w4.w;
                }
            }
        }
    }

    __syncthreads();
    // ---- Wh0 row softmax (row prow; 16 values per thread) ----
    {
        float vmax = -3.0e38f;
#pragma unroll
        for (int h = 0; h < NHEADS; ++h)
#pragma unroll
            for (int c = 0; c < 4; ++c) vmax = fmaxf(vmax, wh0_acc[h][c]);
        vmax = warp16_max(vmax);
        float ex[NHEADS][4];
        float vsum = 0.f;
#pragma unroll
        for (int h = 0; h < NHEADS; ++h)
#pragma unroll
            for (int c = 0; c < 4; ++c) {
                ex[h][c] = __expf(wh0_acc[h][c] - vmax);
                vsum += ex[h][c];
            }
        vsum = warp16_sum(vsum);
        float inv = 1.0f / vsum;
#pragma unroll
        for (int h = 0; h < NHEADS; ++h)
#pragma unroll
            for (int c = 0; c < 4; ++c)
                wh0_lds[prow][h * DHEAD + pc4 + c] = ex[h][c] * inv;
    }
    __syncthreads();

    // ---- epilogue: normalize, add softmax(Wh0), elu, store ----
#pragma unroll
    for (int r = 0; r < 4; ++r) {
        const int row = hrow0 + r;
        const float invL = 1.0f / rowL_lds[row];
        float4 o;
        o.x = hp[r][0] * invL + wh0_lds[row][hc4 + 0];
        o.y = hp[r][1] * invL + wh0_lds[row][hc4 + 1];
        o.z = hp[r][2] * invL + wh0_lds[row][hc4 + 2];
        o.w = hp[r][3] * invL + wh0_lds[row][hc4 + 3];
        o.x = (o.x > 0.f) ? o.x : __expf(o.x) - 1.f;
        o.y = (o.y > 0.f) ? o.y : __expf(o.y) - 1.f;
        o.z = (o.z > 0.f) ? o.z : __expf(o.z) - 1.f;
        o.w = (o.w > 0.f) ? o.w : __expf(o.w) - 1.f;
        *(float4*)&out[(size_t)(i0 + row) * FOUT + hc4] = o;
    }
}

extern "C" void kernel_launch(void* const* d_in, const int* in_sizes, int n_in,
                              void* d_out, int out_size, void* d_ws, size_t ws_size,
                              hipStream_t stream)
{
    const float* h      = (const float*)d_in[0];
    const int*   adj    = (const int*)d_in[1];
    const float* W      = (const float*)d_in[2];
    const float* Wl_w   = (const float*)d_in[3];
    const float* Wl_b   = (const float*)d_in[4];
    const float* Wqkv_w = (const float*)d_in[5];
    const float* Wqkv_b = (const float*)d_in[6];
    const float* a      = (const float*)d_in[7];
    float* out = (float*)d_out;

    float* ws   = (float*)d_ws;
    float* T    = ws;                       // 4096*256
    float* Whb  = ws + 1048576;             // 4096*256
    float* qkvb = ws + 2097152;             // 4096*768
    float* p1b  = ws + 5242880;             // 4096
    float* p2b  = p1b + 4096;               // 4096

    dim3 blk(256);
    // T = h @ W
    gemm_f32<false, false><<<dim3(256 / 64, 4096 / 64), blk, 0, stream>>>(
        h, W, nullptr, T, 4096, 256, 512);
    // Wh = T @ Wl_w^T + Wl_b
    gemm_f32<true, true><<<dim3(256 / 64, 4096 / 64), blk, 0, stream>>>(
        T, Wl_w, Wl_b, Whb, 4096, 256, 256);
    // qkv = Wh @ Wqkv_w^T + Wqkv_b
    gemm_f32<true, true><<<dim3(768 / 64, 4096 / 64), blk, 0, stream>>>(
        Whb, Wqkv_w, Wqkv_b, qkvb, 4096, 768, 256);
    // p1, p2
    compute_p<<<dim3(4096 / 16), blk, 0, stream>>>(Whb, a, p1b, p2b);
    // fused attention
    fused_graph_attn<<<dim3(4096 / TR), blk, 0, stream>>>(qkvb, Whb, p1b, p2b, adj, out);
}

// Round 2
// 585.687 us; speedup vs baseline: 4.6845x; 4.6845x over previous
//
#include <hip/hip_runtime.h>

typedef float  f32x4 __attribute__((ext_vector_type(4)));
typedef short  s16x8 __attribute__((ext_vector_type(8)));

#define NROWS 4096
#define FOUT  256
#define ALPHA_LR 0.2f
#define SCALE 0.0625f
#define NEGV  -9.0e15f
#define KEY64(r) ((((r) ^ ((r) >> 2)) & 3) << 4)

__device__ __forceinline__ unsigned short bf16_rne(float x) {
    unsigned u = __float_as_uint(x);
    u += 0x7fffu + ((u >> 16) & 1u);
    return (unsigned short)(u >> 16);
}
__device__ __forceinline__ unsigned short bf16_trunc(float x) {
    return (unsigned short)(__float_as_uint(x) >> 16);
}
__device__ __forceinline__ float bf2f(unsigned short h) {
    return __uint_as_float(((unsigned)h) << 16);
}
__device__ __forceinline__ float bflo(unsigned u) { return __uint_as_float(u << 16); }
__device__ __forceinline__ float bfhi(unsigned u) { return __uint_as_float(u & 0xffff0000u); }

__device__ __forceinline__ float wmax16(float v) {
#pragma unroll
    for (int o = 8; o; o >>= 1) v = fmaxf(v, __shfl_xor(v, o, 16));
    return v;
}
__device__ __forceinline__ float wsum16(float v) {
#pragma unroll
    for (int o = 8; o; o >>= 1) v += __shfl_xor(v, o, 16);
    return v;
}

// ---------------------------------------------------------------------------
// fp32 GEMM with epilogue modes.
// EPI 0: C[row][col] = v            (float4 stores)
// EPI 1: C = v  AND  o0[col*4096+row] = bf16(v)              (WhT)
// EPI 2: col<256 -> o0/o1 = hi/lo(v) at [row][col]           (q hi/lo)
//        col<512 -> o2/o3 = hi/lo(v) at [row][col-256]       (k hi/lo)
//        else    -> o4[(col-512)*4096+row] = bf16(v)         (vT)
// ---------------------------------------------------------------------------
template <bool BT, bool BIAS, int EPI>
__global__ __launch_bounds__(256) void gemm_f32(
    const float* __restrict__ A, const float* __restrict__ B,
    const float* __restrict__ bias, float* __restrict__ C,
    unsigned short* __restrict__ o0, unsigned short* __restrict__ o1,
    unsigned short* __restrict__ o2, unsigned short* __restrict__ o3,
    unsigned short* __restrict__ o4,
    int M, int Nn, int K)
{
    __shared__ float As[16][68];
    __shared__ float Bs[16][68];

    const int tid = threadIdx.x;
    const int bm = blockIdx.y * 64;
    const int bn = blockIdx.x * 64;
    const int tx = tid & 15;
    const int ty = tid >> 4;

    float acc[4][4];
#pragma unroll
    for (int r = 0; r < 4; ++r)
#pragma unroll
        for (int c = 0; c < 4; ++c) acc[r][c] = 0.0f;

    for (int k0 = 0; k0 < K; k0 += 16) {
        __syncthreads();
        {
            const int r = tid >> 2;
            const int c4 = (tid & 3) * 4;
            float4 a4 = *(const float4*)&A[(size_t)(bm + r) * K + k0 + c4];
            As[c4 + 0][r] = a4.x; As[c4 + 1][r] = a4.y;
            As[c4 + 2][r] = a4.z; As[c4 + 3][r] = a4.w;
        }
        if (!BT) {
            const int r = tid >> 4;
            const int c4 = (tid & 15) * 4;
            *(float4*)&Bs[r][c4] = *(const float4*)&B[(size_t)(k0 + r) * Nn + bn + c4];
        } else {
            const int r = tid >> 2;
            const int c4 = (tid & 3) * 4;
            float4 b4 = *(const float4*)&B[(size_t)(bn + r) * K + k0 + c4];
            Bs[c4 + 0][r] = b4.x; Bs[c4 + 1][r] = b4.y;
            Bs[c4 + 2][r] = b4.z; Bs[c4 + 3][r] = b4.w;
        }
        __syncthreads();
#pragma unroll
        for (int kk = 0; kk < 16; ++kk) {
            float4 a4 = *(const float4*)&As[kk][ty * 4];
            float4 b4 = *(const float4*)&Bs[kk][tx * 4];
            acc[0][0] += a4.x * b4.x; acc[0][1] += a4.x * b4.y; acc[0][2] += a4.x * b4.z; acc[0][3] += a4.x * b4.w;
            acc[1][0] += a4.y * b4.x; acc[1][1] += a4.y * b4.y; acc[1][2] += a4.y * b4.z; acc[1][3] += a4.y * b4.w;
            acc[2][0] += a4.z * b4.x; acc[2][1] += a4.z * b4.y; acc[2][2] += a4.z * b4.z; acc[2][3] += a4.z * b4.w;
            acc[3][0] += a4.w * b4.x; acc[3][1] += a4.w * b4.y; acc[3][2] += a4.w * b4.z; acc[3][3] += a4.w * b4.w;
        }
    }

    float bv[4] = {0.f, 0.f, 0.f, 0.f};
    if (BIAS) {
#pragma unroll
        for (int c = 0; c < 4; ++c) bv[c] = bias[bn + tx * 4 + c];
    }

    if (EPI == 0) {
#pragma unroll
        for (int r = 0; r < 4; ++r) {
            float4 o;
            o.x = acc[r][0] + bv[0]; o.y = acc[r][1] + bv[1];
            o.z = acc[r][2] + bv[2]; o.w = acc[r][3] + bv[3];
            *(float4*)&C[(size_t)(bm + ty * 4 + r) * Nn + bn + tx * 4] = o;
        }
    } else {
#pragma unroll
        for (int r = 0; r < 4; ++r) {
            const int row = bm + ty * 4 + r;
#pragma unroll
            for (int c = 0; c < 4; ++c) {
                const int col = bn + tx * 4 + c;
                float v = acc[r][c] + bv[c];
                if (EPI == 1) {
                    C[(size_t)row * Nn + col] = v;
                    o0[(size_t)col * NROWS + row] = bf16_rne(v);
                } else {
                    if (col < 256) {
                        unsigned short hh = bf16_trunc(v);
                        o0[(size_t)row * 256 + col] = hh;
                        o1[(size_t)row * 256 + col] = bf16_rne(v - bf2f(hh));
                    } else if (col < 512) {
                        unsigned short hh = bf16_trunc(v);
                        o2[(size_t)row * 256 + (col - 256)] = hh;
                        o3[(size_t)row * 256 + (col - 256)] = bf16_rne(v - bf2f(hh));
                    } else {
                        o4[(size_t)(col - 512) * NROWS + row] = bf16_rne(v);
                    }
                }
            }
        }
    }
}

// ---------------------------------------------------------------------------
// p1 = Wh @ a[:256], p2 = Wh @ a[256:]
// ---------------------------------------------------------------------------
__global__ __launch_bounds__(256) void compute_p(
    const float* __restrict__ Wh, const float* __restrict__ a,
    float* __restrict__ p1, float* __restrict__ p2)
{
    const int row = blockIdx.x * 16 + (threadIdx.x >> 4);
    const int c = threadIdx.x & 15;
    float s1 = 0.f, s2 = 0.f;
    for (int f = c; f < FOUT; f += 16) {
        float w = Wh[(size_t)row * FOUT + f];
        s1 += w * a[f];
        s2 += w * a[FOUT + f];
    }
    s1 = wsum16(s1);
    s2 = wsum16(s2);
    if (c == 0) { p1[row] = s1; p2[row] = s2; }
}

// ---------------------------------------------------------------------------
// Fused MFMA attention. Block = 256 threads = 4 waves, wave w = head w.
// 16 output rows per block (grid 256). Two sweeps over j (inner stats, then
// dots/PV/outer-flash/A@Wh). bf16 hi/lo split for QK^T.
// ---------------------------------------------------------------------------
__global__ __launch_bounds__(256) void fused_attn(
    const unsigned short* __restrict__ qh_g, const unsigned short* __restrict__ ql_g,
    const unsigned short* __restrict__ kh_g, const unsigned short* __restrict__ kl_g,
    const unsigned short* __restrict__ vth_g, const unsigned short* __restrict__ wht_g,
    const float* __restrict__ p1g, const float* __restrict__ p2g,
    const int* __restrict__ adj, float* __restrict__ out)
{
    // LDS layout (bytes). K-region (32KB) is reused for vT/WhT and Wh0.
    enum { KH = 0, KL = 16384, VTH = 0, WHT = 16384, WH0 = 0,
           DOTS = 32768, PTIL = 36864,
           P1S = 37888, ROWM = 37952, ROWL = 38016, ALP = 38080, SMEMSZ = 38176 };
    __shared__ __align__(16) char smem[SMEMSZ];
    float* smF = (float*)smem;

    const int tid = threadIdx.x;
    const int w   = tid >> 6;        // head
    const int ln  = tid & 63;
    const int l15 = ln & 15;
    const int lhi = ln >> 4;         // 0..3
    const int i0  = blockIdx.x * 16;

    if (tid < 16) {
        ((float*)(smem + P1S))[tid]  = p1g[i0 + tid];
        ((float*)(smem + ROWM))[tid] = -3.0e38f;
        ((float*)(smem + ROWL))[tid] = 0.0f;
        ((float*)(smem + ALP))[tid]  = 1.0f;
    }

    // ---- q fragments (A-operand), persistent in registers ----
    s16x8 qhA[2], qlA[2];
#pragma unroll
    for (int ks = 0; ks < 2; ++ks) {
        size_t off = (size_t)(i0 + l15) * 256 + w * 64 + ks * 32 + lhi * 8;
        qhA[ks] = *(const s16x8*)(qh_g + off);
        qlA[ks] = *(const s16x8*)(ql_g + off);
    }

    // ---- constant per-thread fragment addresses ----
    const int kswz = (l15 & 7) << 4;
    int kaddr[2][2];
#pragma unroll
    for (int nt = 0; nt < 2; ++nt)
#pragma unroll
        for (int ks = 0; ks < 2; ++ks)
            kaddr[nt][ks] = (nt * 16 + l15) * 512 + ((w * 128 + ks * 64 + lhi * 16) ^ kswz);

    const int dA_addr = DOTS + w * 1024 + l15 * 64 + ((lhi * 16) ^ KEY64(l15));
    const int pA_addr = PTIL + l15 * 64 + ((lhi * 16) ^ KEY64(l15));
    int vB_addr[4];
#pragma unroll
    for (int nt = 0; nt < 4; ++nt) {
        int dr = w * 64 + nt * 16 + l15;
        vB_addr[nt] = dr * 64 + ((lhi * 16) ^ KEY64(dr));
    }

    // ================= sweep 1: inner-attention stats =================
    float m[4], z[4];
#pragma unroll
    for (int r = 0; r < 4; ++r) { m[r] = -3.0e38f; z[r] = 0.f; }

    for (int j0 = 0; j0 < NROWS; j0 += 32) {
        __syncthreads();
#pragma unroll
        for (int t = 0; t < 4; ++t) {
            int c = tid + t * 256; int jj = c >> 5; int ck = c & 31;
            int la = jj * 512 + ((ck * 16) ^ ((jj & 7) << 4));
            size_t ga = (size_t)(j0 + jj) * 256 + ck * 8;
            *(uint4*)(smem + KH + la) = *(const uint4*)(kh_g + ga);
            *(uint4*)(smem + KL + la) = *(const uint4*)(kl_g + ga);
        }
        __syncthreads();
        f32x4 acc[2] = {{0.f,0.f,0.f,0.f},{0.f,0.f,0.f,0.f}};
#pragma unroll
        for (int ks = 0; ks < 2; ++ks) {
#pragma unroll
            for (int nt = 0; nt < 2; ++nt) {
                s16x8 k8h = *(const s16x8*)(smem + KH + kaddr[nt][ks]);
                s16x8 k8l = *(const s16x8*)(smem + KL + kaddr[nt][ks]);
                acc[nt] = __builtin_amdgcn_mfma_f32_16x16x32_bf16(qhA[ks], k8h, acc[nt], 0, 0, 0);
                acc[nt] = __builtin_amdgcn_mfma_f32_16x16x32_bf16(qhA[ks], k8l, acc[nt], 0, 0, 0);
                acc[nt] = __builtin_amdgcn_mfma_f32_16x16x32_bf16(qlA[ks], k8h, acc[nt], 0, 0, 0);
            }
        }
#pragma unroll
        for (int r = 0; r < 4; ++r) {
            float s0 = acc[0][r] * SCALE, s1 = acc[1][r] * SCALE;
            float tm = wmax16(fmaxf(s0, s1));
            float mn = fmaxf(m[r], tm);
            float e = __expf(s0 - mn) + __expf(s1 - mn);
            e = wsum16(e);
            z[r] = z[r] * __expf(m[r] - mn) + e;
            m[r] = mn;
        }
    }
    float iz[4];
#pragma unroll
    for (int r = 0; r < 4; ++r) iz[r] = 1.0f / z[r];

    // ================= sweep 2 =================
    f32x4 pacc[4], wacc[4];
#pragma unroll
    for (int nt = 0; nt < 4; ++nt) {
        pacc[nt] = (f32x4){0.f, 0.f, 0.f, 0.f};
        wacc[nt] = (f32x4){0.f, 0.f, 0.f, 0.f};
    }
    const int orow = tid >> 4;
    const int oc2  = (tid & 15) * 2;
    const float p1v = ((float*)(smem + P1S))[orow];

    for (int j0 = 0; j0 < NROWS; j0 += 32) {
        __syncthreads();   // prev tile fully consumed
#pragma unroll
        for (int t = 0; t < 4; ++t) {
            int c = tid + t * 256; int jj = c >> 5; int ck = c & 31;
            int la = jj * 512 + ((ck * 16) ^ ((jj & 7) << 4));
            size_t ga = (size_t)(j0 + jj) * 256 + ck * 8;
            *(uint4*)(smem + KH + la) = *(const uint4*)(kh_g + ga);
            *(uint4*)(smem + KL + la) = *(const uint4*)(kl_g + ga);
        }
        __syncthreads();
        f32x4 acc[2] = {{0.f,0.f,0.f,0.f},{0.f,0.f,0.f,0.f}};
#pragma unroll
        for (int ks = 0; ks < 2; ++ks) {
#pragma unroll
            for (int nt = 0; nt < 2; ++nt) {
                s16x8 k8h = *(const s16x8*)(smem + KH + kaddr[nt][ks]);
                s16x8 k8l = *(const s16x8*)(smem + KL + kaddr[nt][ks]);
                acc[nt] = __builtin_amdgcn_mfma_f32_16x16x32_bf16(qhA[ks], k8h, acc[nt], 0, 0, 0);
                acc[nt] = __builtin_amdgcn_mfma_f32_16x16x32_bf16(qhA[ks], k8l, acc[nt], 0, 0, 0);
                acc[nt] = __builtin_amdgcn_mfma_f32_16x16x32_bf16(qlA[ks], k8h, acc[nt], 0, 0, 0);
            }
        }
        // dots = exp(s - m) * iz  -> LDS (bf16, swizzled)
#pragma unroll
        for (int nt = 0; nt < 2; ++nt)
#pragma unroll
            for (int r = 0; r < 4; ++r) {
                float d = __expf(acc[nt][r] * SCALE - m[r]) * iz[r];
                int row = lhi * 4 + r;
                int cb = (nt * 16 + l15) * 2;
                *(unsigned short*)(smem + DOTS + w * 1024 + row * 64 + (cb ^ KEY64(row))) = bf16_rne(d);
            }
        __syncthreads();   // dots visible; K region free
        // stage vT, WhT over the K region
#pragma unroll
        for (int t = 0; t < 4; ++t) {
            int c = tid + t * 256; int d = c >> 2; int ck = c & 3;
            int la = d * 64 + ((ck * 16) ^ KEY64(d));
            size_t ga = (size_t)d * NROWS + j0 + ck * 8;
            *(uint4*)(smem + VTH + la) = *(const uint4*)(vth_g + ga);
            *(uint4*)(smem + WHT + la) = *(const uint4*)(wht_g + ga);
        }
        __syncthreads();
        // PV (wave's own head)
        {
            s16x8 dA = *(const s16x8*)(smem + dA_addr);
#pragma unroll
            for (int nt = 0; nt < 4; ++nt) {
                s16x8 vB = *(const s16x8*)(smem + VTH + vB_addr[nt]);
                pacc[nt] = __builtin_amdgcn_mfma_f32_16x16x32_bf16(dA, vB, pacc[nt], 0, 0, 0);
            }
        }
        // outer masked flash softmax (2 cells/thread)
        {
            float ds0 = 0.f, ds1 = 0.f;
#pragma unroll
            for (int hh = 0; hh < 4; ++hh) {
                unsigned u = *(const unsigned*)(smem + DOTS + hh * 1024 + orow * 64 + ((oc2 * 2) ^ KEY64(orow)));
                ds0 += bflo(u); ds1 += bfhi(u);
            }
            float2 p2v = *(const float2*)(p2g + j0 + oc2);
            int2 av = *(const int2*)(adj + (size_t)(i0 + orow) * NROWS + j0 + oc2);
            float e0 = p1v + p2v.x; e0 = e0 > 0.f ? e0 : ALPHA_LR * e0;
            float e1 = p1v + p2v.y; e1 = e1 > 0.f ? e1 : ALPHA_LR * e1;
            float l0 = av.x > 0 ? e0 + ds0 : NEGV;
            float l1 = av.y > 0 ? e1 + ds1 : NEGV;
            float tm = wmax16(fmaxf(l0, l1));
            float Mo = ((float*)(smem + ROWM))[orow];
            float Mn = fmaxf(Mo, tm);
            float p0 = __expf(l0 - Mn), p1e = __expf(l1 - Mn);
            float ps = wsum16(p0 + p1e);
            if ((tid & 15) == 0) {
                float al = __expf(Mo - Mn);
                ((float*)(smem + ROWM))[orow] = Mn;
                ((float*)(smem + ROWL))[orow] = ((float*)(smem + ROWL))[orow] * al + ps;
                ((float*)(smem + ALP))[orow]  = al;
            }
            unsigned pk = (unsigned)bf16_rne(p0) | ((unsigned)bf16_rne(p1e) << 16);
            *(unsigned*)(smem + PTIL + orow * 64 + ((oc2 * 2) ^ KEY64(orow))) = pk;
        }
        __syncthreads();   // ptil + alpha visible
        // A@Wh with flash rescale
        {
            f32x4 av;
#pragma unroll
            for (int r = 0; r < 4; ++r) av[r] = ((float*)(smem + ALP))[lhi * 4 + r];
#pragma unroll
            for (int nt = 0; nt < 4; ++nt) wacc[nt] *= av;
            s16x8 pA = *(const s16x8*)(smem + pA_addr);
#pragma unroll
            for (int nt = 0; nt < 4; ++nt) {
                s16x8 wB = *(const s16x8*)(smem + WHT + vB_addr[nt]);
                wacc[nt] = __builtin_amdgcn_mfma_f32_16x16x32_bf16(pA, wB, wacc[nt], 0, 0, 0);
            }
        }
    }

    // ================= epilogue =================
    __syncthreads();
    // PV acc -> Wh0 (f32 [16][256]) over the staging region
#pragma unroll
    for (int nt = 0; nt < 4; ++nt)
#pragma unroll
        for (int r = 0; r < 4; ++r)
            smF[(lhi * 4 + r) * 256 + (w * 64 + nt * 16 + l15)] = pacc[nt][r];
    __syncthreads();
    // Wh0 row softmax in place
    {
        const int rt = tid >> 4;
        const int cb = (tid & 15) * 4;
        float4 vals[4];
        float mx = -3.0e38f;
#pragma unroll
        for (int k = 0; k < 4; ++k) {
            vals[k] = *(float4*)&smF[rt * 256 + cb + k * 64];
            mx = fmaxf(mx, fmaxf(fmaxf(vals[k].x, vals[k].y), fmaxf(vals[k].z, vals[k].w)));
        }
        mx = wmax16(mx);
        float sm = 0.f;
#pragma unroll
        for (int k = 0; k < 4; ++k) {
            vals[k].x = __expf(vals[k].x - mx); vals[k].y = __expf(vals[k].y - mx);
            vals[k].z = __expf(vals[k].z - mx); vals[k].w = __expf(vals[k].w - mx);
            sm += vals[k].x + vals[k].y + vals[k].z + vals[k].w;
        }
        sm = wsum16(sm);
        float inv = 1.0f / sm;
#pragma unroll
        for (int k = 0; k < 4; ++k) {
            vals[k].x *= inv; vals[k].y *= inv; vals[k].z *= inv; vals[k].w *= inv;
            *(float4*)&smF[rt * 256 + cb + k * 64] = vals[k];
        }
    }
    __syncthreads();
    // combine, elu, store
    {
        float invL[4];
#pragma unroll
        for (int r = 0; r < 4; ++r) invL[r] = 1.0f / ((float*)(smem + ROWL))[lhi * 4 + r];
#pragma unroll
        for (int nt = 0; nt < 4; ++nt)
#pragma unroll
            for (int r = 0; r < 4; ++r) {
                int row = lhi * 4 + r;
                int f = w * 64 + nt * 16 + l15;
                float v = wacc[nt][r] * invL[r] + smF[row * 256 + f];
                out[(size_t)(i0 + row) * FOUT + f] = v > 0.f ? v : __expf(v) - 1.f;
            }
    }
}

extern "C" void kernel_launch(void* const* d_in, const int* in_sizes, int n_in,
                              void* d_out, int out_size, void* d_ws, size_t ws_size,
                              hipStream_t stream)
{
    const float* h      = (const float*)d_in[0];
    const int*   adj    = (const int*)d_in[1];
    const float* W      = (const float*)d_in[2];
    const float* Wl_w   = (const float*)d_in[3];
    const float* Wl_b   = (const float*)d_in[4];
    const float* Wqkv_w = (const float*)d_in[5];
    const float* Wqkv_b = (const float*)d_in[6];
    const float* a      = (const float*)d_in[7];
    float* out = (float*)d_out;

    float* ws = (float*)d_ws;
    float* T   = ws;                              // 1M floats
    float* Whb = ws + (1 << 20);                  // 1M floats
    unsigned short* u16b = (unsigned short*)(ws + (2 << 20));
    unsigned short* qh  = u16b;                   // 1M u16 each
    unsigned short* ql  = qh  + (1 << 20);
    unsigned short* kh  = ql  + (1 << 20);
    unsigned short* kl  = kh  + (1 << 20);
    unsigned short* vth = kl  + (1 << 20);
    unsigned short* wht = vth + (1 << 20);
    float* p1b = ws + (5 << 20);
    float* p2b = p1b + 4096;

    dim3 blk(256);
    gemm_f32<false, false, 0><<<dim3(4, 64), blk, 0, stream>>>(
        h, W, nullptr, T, nullptr, nullptr, nullptr, nullptr, nullptr, 4096, 256, 512);
    gemm_f32<true, true, 1><<<dim3(4, 64), blk, 0, stream>>>(
        T, Wl_w, Wl_b, Whb, wht, nullptr, nullptr, nullptr, nullptr, 4096, 256, 256);
    gemm_f32<true, true, 2><<<dim3(12, 64), blk, 0, stream>>>(
        Whb, Wqkv_w, Wqkv_b, nullptr, qh, ql, kh, kl, vth, 4096, 768, 256);
    compute_p<<<dim3(256), blk, 0, stream>>>(Whb, a, p1b, p2b);
    fused_attn<<<dim3(256), blk, 0, stream>>>(qh, ql, kh, kl, vth, wht, p1b, p2b, adj, out);
}

// Round 3
// 552.167 us; speedup vs baseline: 4.9689x; 1.0607x over previous
//
#include <hip/hip_runtime.h>

typedef float  f32x4 __attribute__((ext_vector_type(4)));
typedef short  s16x8 __attribute__((ext_vector_type(8)));

#define NROWS 4096
#define FOUT  256
#define ALPHA_LR 0.2f
#define SCALE 0.0625f
#define NEGV  -9.0e15f
#define KEY64(r) ((((r) ^ ((r) >> 2)) & 3) << 4)

static __device__ __forceinline__ unsigned short bf16_rne(float x) {
    unsigned u = __float_as_uint(x);
    u += 0x7fffu + ((u >> 16) & 1u);
    return (unsigned short)(u >> 16);
}
static __device__ __forceinline__ unsigned short bf16_trunc(float x) {
    return (unsigned short)(__float_as_uint(x) >> 16);
}
static __device__ __forceinline__ float bf2f(unsigned short h) {
    return __uint_as_float(((unsigned)h) << 16);
}
static __device__ __forceinline__ float bflo(unsigned u) { return __uint_as_float(u << 16); }
static __device__ __forceinline__ float bfhi(unsigned u) { return __uint_as_float(u & 0xffff0000u); }

static __device__ __forceinline__ float wmax16(float v) {
#pragma unroll
    for (int o = 8; o; o >>= 1) v = fmaxf(v, __shfl_xor(v, o, 16));
    return v;
}
static __device__ __forceinline__ float wsum16(float v) {
#pragma unroll
    for (int o = 8; o; o >>= 1) v += __shfl_xor(v, o, 16);
    return v;
}

// ---------------------------------------------------------------------------
// fp32 GEMM with epilogue modes (unchanged from round 2).
// ---------------------------------------------------------------------------
template <bool BT, bool BIAS, int EPI>
__global__ __launch_bounds__(256) void gemm_f32(
    const float* __restrict__ A, const float* __restrict__ B,
    const float* __restrict__ bias, float* __restrict__ C,
    unsigned short* __restrict__ o0, unsigned short* __restrict__ o1,
    unsigned short* __restrict__ o2, unsigned short* __restrict__ o3,
    unsigned short* __restrict__ o4,
    int M, int Nn, int K)
{
    __shared__ float As[16][68];
    __shared__ float Bs[16][68];

    const int tid = threadIdx.x;
    const int bm = blockIdx.y * 64;
    const int bn = blockIdx.x * 64;
    const int tx = tid & 15;
    const int ty = tid >> 4;

    float acc[4][4];
#pragma unroll
    for (int r = 0; r < 4; ++r)
#pragma unroll
        for (int c = 0; c < 4; ++c) acc[r][c] = 0.0f;

    for (int k0 = 0; k0 < K; k0 += 16) {
        __syncthreads();
        {
            const int r = tid >> 2;
            const int c4 = (tid & 3) * 4;
            float4 a4 = *(const float4*)&A[(size_t)(bm + r) * K + k0 + c4];
            As[c4 + 0][r] = a4.x; As[c4 + 1][r] = a4.y;
            As[c4 + 2][r] = a4.z; As[c4 + 3][r] = a4.w;
        }
        if (!BT) {
            const int r = tid >> 4;
            const int c4 = (tid & 15) * 4;
            *(float4*)&Bs[r][c4] = *(const float4*)&B[(size_t)(k0 + r) * Nn + bn + c4];
        } else {
            const int r = tid >> 2;
            const int c4 = (tid & 3) * 4;
            float4 b4 = *(const float4*)&B[(size_t)(bn + r) * K + k0 + c4];
            Bs[c4 + 0][r] = b4.x; Bs[c4 + 1][r] = b4.y;
            Bs[c4 + 2][r] = b4.z; Bs[c4 + 3][r] = b4.w;
        }
        __syncthreads();
#pragma unroll
        for (int kk = 0; kk < 16; ++kk) {
            float4 a4 = *(const float4*)&As[kk][ty * 4];
            float4 b4 = *(const float4*)&Bs[kk][tx * 4];
            acc[0][0] += a4.x * b4.x; acc[0][1] += a4.x * b4.y; acc[0][2] += a4.x * b4.z; acc[0][3] += a4.x * b4.w;
            acc[1][0] += a4.y * b4.x; acc[1][1] += a4.y * b4.y; acc[1][2] += a4.y * b4.z; acc[1][3] += a4.y * b4.w;
            acc[2][0] += a4.z * b4.x; acc[2][1] += a4.z * b4.y; acc[2][2] += a4.z * b4.z; acc[2][3] += a4.z * b4.w;
            acc[3][0] += a4.w * b4.x; acc[3][1] += a4.w * b4.y; acc[3][2] += a4.w * b4.z; acc[3][3] += a4.w * b4.w;
        }
    }

    float bv[4] = {0.f, 0.f, 0.f, 0.f};
    if (BIAS) {
#pragma unroll
        for (int c = 0; c < 4; ++c) bv[c] = bias[bn + tx * 4 + c];
    }

    if (EPI == 0) {
#pragma unroll
        for (int r = 0; r < 4; ++r) {
            float4 o;
            o.x = acc[r][0] + bv[0]; o.y = acc[r][1] + bv[1];
            o.z = acc[r][2] + bv[2]; o.w = acc[r][3] + bv[3];
            *(float4*)&C[(size_t)(bm + ty * 4 + r) * Nn + bn + tx * 4] = o;
        }
    } else {
#pragma unroll
        for (int r = 0; r < 4; ++r) {
            const int row = bm + ty * 4 + r;
#pragma unroll
            for (int c = 0; c < 4; ++c) {
                const int col = bn + tx * 4 + c;
                float v = acc[r][c] + bv[c];
                if (EPI == 1) {
                    C[(size_t)row * Nn + col] = v;
                    o0[(size_t)col * NROWS + row] = bf16_rne(v);
                } else {
                    if (col < 256) {
                        unsigned short hh = bf16_trunc(v);
                        o0[(size_t)row * 256 + col] = hh;
                        o1[(size_t)row * 256 + col] = bf16_rne(v - bf2f(hh));
                    } else if (col < 512) {
                        unsigned short hh = bf16_trunc(v);
                        o2[(size_t)row * 256 + (col - 256)] = hh;
                        o3[(size_t)row * 256 + (col - 256)] = bf16_rne(v - bf2f(hh));
                    } else {
                        o4[(size_t)(col - 512) * NROWS + row] = bf16_rne(v);
                    }
                }
            }
        }
    }
}

// ---------------------------------------------------------------------------
// p1 = Wh @ a[:256], p2 = Wh @ a[256:]
// ---------------------------------------------------------------------------
__global__ __launch_bounds__(256) void compute_p(
    const float* __restrict__ Wh, const float* __restrict__ a,
    float* __restrict__ p1, float* __restrict__ p2)
{
    const int row = blockIdx.x * 16 + (threadIdx.x >> 4);
    const int c = threadIdx.x & 15;
    float s1 = 0.f, s2 = 0.f;
    for (int f = c; f < FOUT; f += 16) {
        float w = Wh[(size_t)row * FOUT + f];
        s1 += w * a[f];
        s2 += w * a[FOUT + f];
    }
    s1 = wsum16(s1);
    s2 = wsum16(s2);
    if (c == 0) { p1[row] = s1; p2[row] = s2; }
}

// ---------------------------------------------------------------------------
// Fused MFMA attention, pipelined. 512 threads = 8 waves = (row-group g 0..1)
// x (head h 0..3). 32 output rows per block, grid 128. Reg-staged double
// buffering: loads for tile t+1 issue at top of tile t, LDS writes land late.
// ---------------------------------------------------------------------------
__global__ __launch_bounds__(512, 2) void fused_attn(
    const unsigned short* __restrict__ qh_g, const unsigned short* __restrict__ ql_g,
    const unsigned short* __restrict__ kh_g, const unsigned short* __restrict__ kl_g,
    const unsigned short* __restrict__ vth_g, const unsigned short* __restrict__ wht_g,
    const float* __restrict__ p1g, const float* __restrict__ p2g,
    const int* __restrict__ adj, float* __restrict__ out)
{
    enum { KH_ = 0, KL_ = 16384, VT_ = 32768, WHT_ = 49152,
           DOTS_ = 81920, PTIL_ = 90112, ALP_ = 92160, RL_ = 92288,
           SMEMSZ = 92416 };
    __shared__ __align__(16) char smem[SMEMSZ];
    float* smF = (float*)smem;

    const int tid = threadIdx.x;
    const int w   = tid >> 6;
    const int g   = w >> 2;          // row-group (rows g*16 .. +15)
    const int h   = w & 3;           // head
    const int ln  = tid & 63;
    const int l15 = ln & 15;
    const int lhi = ln >> 4;
    const int i0  = blockIdx.x * 32;
    const int orow = tid >> 4;       // 0..31 (outer-softmax row)
    const int oc2  = (tid & 15) * 2; // 2 cols per thread

    // ---- staging descriptors (per thread, 2 x 16B each array) ----
    int gko[2], laK[2], gvo[2], laV[2];
#pragma unroll
    for (int it = 0; it < 2; ++it) {
        int c = tid + it * 512;
        int jj = c >> 5, ck = c & 31;
        gko[it] = jj * 256 + ck * 8;
        laK[it] = jj * 512 + ((ck * 16) ^ ((jj & 7) << 4));
        int d = c >> 2, cv = c & 3;
        gvo[it] = d * 4096 + cv * 8;
        laV[it] = d * 64 + ((cv * 16) ^ KEY64(d));
    }

    // ---- persistent q fragments ----
    s16x8 qhA[2], qlA[2];
#pragma unroll
    for (int ks = 0; ks < 2; ++ks) {
        size_t off = (size_t)(i0 + g * 16 + l15) * 256 + h * 64 + ks * 32 + lhi * 8;
        qhA[ks] = *(const s16x8*)(qh_g + off);
        qlA[ks] = *(const s16x8*)(ql_g + off);
    }

    int kaddr[2][2];
#pragma unroll
    for (int nt = 0; nt < 2; ++nt)
#pragma unroll
        for (int ks = 0; ks < 2; ++ks)
            kaddr[nt][ks] = (nt * 16 + l15) * 512 +
                            ((h * 128 + ks * 64 + lhi * 16) ^ ((l15 & 7) << 4));

    const int dArow = g * 16 + l15;
    const int dA_off = h * 2048 + dArow * 64 + ((lhi * 16) ^ KEY64(dArow));
    const int pA_off = dArow * 64 + ((lhi * 16) ^ KEY64(dArow));
    int vB_off[4];
#pragma unroll
    for (int nt = 0; nt < 4; ++nt) {
        int dr = h * 64 + nt * 16 + l15;
        vB_off[nt] = dr * 64 + ((lhi * 16) ^ KEY64(dr));
    }

    // ================= sweep 1: inner stats (hi-term only) =================
#pragma unroll
    for (int it = 0; it < 2; ++it)
        *(uint4*)(smem + KH_ + laK[it]) = *(const uint4*)(kh_g + gko[it]);
    __syncthreads();

    float m[4], z[4];
#pragma unroll
    for (int r = 0; r < 4; ++r) { m[r] = -3.0e38f; z[r] = 0.f; }
    int kb = 0;
    for (int t = 0; t < 128; ++t) {
        const int jn = ((t + 1) & 127) * 32;
        uint4 khr[2];
#pragma unroll
        for (int it = 0; it < 2; ++it)
            khr[it] = *(const uint4*)(kh_g + (size_t)jn * 256 + gko[it]);
        const char* kp = smem + (kb ? WHT_ : KH_);
        f32x4 acc[2] = {{0.f,0.f,0.f,0.f},{0.f,0.f,0.f,0.f}};
        __builtin_amdgcn_s_setprio(1);
#pragma unroll
        for (int ks = 0; ks < 2; ++ks)
#pragma unroll
            for (int nt = 0; nt < 2; ++nt) {
                s16x8 k8 = *(const s16x8*)(kp + kaddr[nt][ks]);
                acc[nt] = __builtin_amdgcn_mfma_f32_16x16x32_bf16(qhA[ks], k8, acc[nt], 0, 0, 0);
            }
        __builtin_amdgcn_s_setprio(0);
#pragma unroll
        for (int r = 0; r < 4; ++r) {
            float s0 = acc[0][r] * SCALE, s1 = acc[1][r] * SCALE;
            float mn = fmaxf(m[r], fmaxf(s0, s1));
            z[r] = z[r] * __expf(m[r] - mn) + __expf(s0 - mn) + __expf(s1 - mn);
            m[r] = mn;
        }
        char* kw = smem + (kb ? KH_ : WHT_);
#pragma unroll
        for (int it = 0; it < 2; ++it)
            *(uint4*)(kw + laK[it]) = khr[it];
        __syncthreads();
        kb ^= 1;
    }
    float iz[4];
#pragma unroll
    for (int r = 0; r < 4; ++r) {
        float mm = m[r], zz = z[r];
#pragma unroll
        for (int off = 1; off < 16; off <<= 1) {
            float mo = __shfl_xor(mm, off, 16);
            float zo = __shfl_xor(zz, off, 16);
            float mn = fmaxf(mm, mo);
            zz = zz * __expf(mm - mn) + zo * __expf(mo - mn);
            mm = mn;
        }
        m[r] = mm;
        iz[r] = 1.0f / zz;
    }

    // ================= sweep 2 prologue =================
#pragma unroll
    for (int it = 0; it < 2; ++it) {
        *(uint4*)(smem + KH_ + laK[it]) = *(const uint4*)(kh_g + gko[it]);
        *(uint4*)(smem + KL_ + laK[it]) = *(const uint4*)(kl_g + gko[it]);
        *(uint4*)(smem + VT_ + laV[it]) = *(const uint4*)(vth_g + gvo[it]);
        *(uint4*)(smem + WHT_ + laV[it]) = *(const uint4*)(wht_g + gvo[it]);
    }
    __syncthreads();

    f32x4 pacc[4], wacc[4];
#pragma unroll
    for (int nt = 0; nt < 4; ++nt) {
        pacc[nt] = (f32x4){0.f,0.f,0.f,0.f};
        wacc[nt] = (f32x4){0.f,0.f,0.f,0.f};
    }
    float Mrun = -3.0e38f, Lrun = 0.0f;
    const float p1v = p1g[i0 + orow];
    int whb = 0;

    for (int t = 0; t < 128; ++t) {
        const int j0 = t * 32;
        const int jn = ((t + 1) & 127) * 32;
        // async issue: tile t+1 operands + this tile's adj/p2
        uint4 khr[2], klr[2], vr[2], wr[2];
#pragma unroll
        for (int it = 0; it < 2; ++it) {
            size_t gk = (size_t)jn * 256 + gko[it];
            khr[it] = *(const uint4*)(kh_g + gk);
            klr[it] = *(const uint4*)(kl_g + gk);
            size_t gv = (size_t)jn + gvo[it];
            vr[it] = *(const uint4*)(vth_g + gv);
            wr[it] = *(const uint4*)(wht_g + gv);
        }
        int2 av = *(const int2*)(adj + (size_t)(i0 + orow) * NROWS + j0 + oc2);
        float2 pv2 = *(const float2*)(p2g + j0 + oc2);

        // ---- QK (exact 3-term hi/lo) ----
        f32x4 acc[2] = {{0.f,0.f,0.f,0.f},{0.f,0.f,0.f,0.f}};
        __builtin_amdgcn_s_setprio(1);
#pragma unroll
        for (int ks = 0; ks < 2; ++ks)
#pragma unroll
            for (int nt = 0; nt < 2; ++nt) {
                s16x8 k8h = *(const s16x8*)(smem + KH_ + kaddr[nt][ks]);
                s16x8 k8l = *(const s16x8*)(smem + KL_ + kaddr[nt][ks]);
                acc[nt] = __builtin_amdgcn_mfma_f32_16x16x32_bf16(qhA[ks], k8h, acc[nt], 0, 0, 0);
                acc[nt] = __builtin_amdgcn_mfma_f32_16x16x32_bf16(qhA[ks], k8l, acc[nt], 0, 0, 0);
                acc[nt] = __builtin_amdgcn_mfma_f32_16x16x32_bf16(qlA[ks], k8h, acc[nt], 0, 0, 0);
            }
        __builtin_amdgcn_s_setprio(0);
        // dots -> LDS (bf16, swizzled)
#pragma unroll
        for (int nt = 0; nt < 2; ++nt)
#pragma unroll
            for (int r = 0; r < 4; ++r) {
                int row = g * 16 + lhi * 4 + r;
                float d = __expf(acc[nt][r] * SCALE - m[r]) * iz[r];
                *(unsigned short*)(smem + DOTS_ + h * 2048 + row * 64 +
                                   (((nt * 16 + l15) * 2) ^ KEY64(row))) = bf16_rne(d);
            }
        __syncthreads();  // B1: dots visible, K region free

        // K(t+1) LDS write
#pragma unroll
        for (int it = 0; it < 2; ++it) {
            *(uint4*)(smem + KH_ + laK[it]) = khr[it];
            *(uint4*)(smem + KL_ + laK[it]) = klr[it];
        }
        // ---- PV ----
        {
            s16x8 dA = *(const s16x8*)(smem + DOTS_ + dA_off);
            __builtin_amdgcn_s_setprio(1);
#pragma unroll
            for (int nt = 0; nt < 4; ++nt) {
                s16x8 vB = *(const s16x8*)(smem + VT_ + vB_off[nt]);
                pacc[nt] = __builtin_amdgcn_mfma_f32_16x16x32_bf16(dA, vB, pacc[nt], 0, 0, 0);
            }
            __builtin_amdgcn_s_setprio(0);
        }
        // ---- outer masked flash softmax ----
        {
            float ds0 = 0.f, ds1 = 0.f;
#pragma unroll
            for (int hh = 0; hh < 4; ++hh) {
                unsigned u = *(const unsigned*)(smem + DOTS_ + hh * 2048 + orow * 64 +
                                                ((oc2 * 2) ^ KEY64(orow)));
                ds0 += bflo(u); ds1 += bfhi(u);
            }
            float e0 = p1v + pv2.x; e0 = e0 > 0.f ? e0 : ALPHA_LR * e0;
            float e1 = p1v + pv2.y; e1 = e1 > 0.f ? e1 : ALPHA_LR * e1;
            float l0 = av.x > 0 ? e0 + ds0 : NEGV;
            float l1 = av.y > 0 ? e1 + ds1 : NEGV;
            float tm = wmax16(fmaxf(l0, l1));
            float Mn = fmaxf(Mrun, tm);
            float p0 = __expf(l0 - Mn), p1e = __expf(l1 - Mn);
            float ps = wsum16(p0 + p1e);
            float al = __expf(Mrun - Mn);
            Lrun = Lrun * al + ps;
            Mrun = Mn;
            if ((tid & 15) == 0) *(float*)(smem + ALP_ + orow * 4) = al;
            unsigned pk = (unsigned)bf16_rne(p0) | ((unsigned)bf16_rne(p1e) << 16);
            *(unsigned*)(smem + PTIL_ + orow * 64 + ((oc2 * 2) ^ KEY64(orow))) = pk;
        }
        __syncthreads();  // B2: ptil/alpha visible, V region free

        // V(t+1), Wh(t+1) LDS writes
#pragma unroll
        for (int it = 0; it < 2; ++it) {
            *(uint4*)(smem + VT_ + laV[it]) = vr[it];
            *(uint4*)(smem + WHT_ + (whb ^ 16384) + laV[it]) = wr[it];
        }
        // ---- A@Wh with flash rescale ----
        {
            float alr[4];
#pragma unroll
            for (int r = 0; r < 4; ++r)
                alr[r] = *(const float*)(smem + ALP_ + (g * 16 + lhi * 4 + r) * 4);
#pragma unroll
            for (int nt = 0; nt < 4; ++nt)
#pragma unroll
                for (int r = 0; r < 4; ++r) wacc[nt][r] *= alr[r];
            s16x8 pA = *(const s16x8*)(smem + PTIL_ + pA_off);
            __builtin_amdgcn_s_setprio(1);
#pragma unroll
            for (int nt = 0; nt < 4; ++nt) {
                s16x8 wB = *(const s16x8*)(smem + WHT_ + whb + vB_off[nt]);
                wacc[nt] = __builtin_amdgcn_mfma_f32_16x16x32_bf16(pA, wB, wacc[nt], 0, 0, 0);
            }
            __builtin_amdgcn_s_setprio(0);
        }
        whb ^= 16384;
        __syncthreads();  // B3: staged tile t+1 ready everywhere
    }

    // ================= epilogue =================
    if ((tid & 15) == 0) *(float*)(smem + RL_ + orow * 4) = Lrun;
    // pacc -> Wh0 f32 [32][256] over K region
#pragma unroll
    for (int nt = 0; nt < 4; ++nt)
#pragma unroll
        for (int r = 0; r < 4; ++r)
            smF[(g * 16 + lhi * 4 + r) * 256 + h * 64 + nt * 16 + l15] = pacc[nt][r];
    __syncthreads();
    // Wh0 row softmax in place
    {
        const int rt = tid >> 4;
        const int cb = (tid & 15) * 4;
        float4 vals[4];
        float mx = -3.0e38f;
#pragma unroll
        for (int k = 0; k < 4; ++k) {
            vals[k] = *(float4*)&smF[rt * 256 + cb + k * 64];
            mx = fmaxf(mx, fmaxf(fmaxf(vals[k].x, vals[k].y), fmaxf(vals[k].z, vals[k].w)));
        }
        mx = wmax16(mx);
        float sm = 0.f;
#pragma unroll
        for (int k = 0; k < 4; ++k) {
            vals[k].x = __expf(vals[k].x - mx); vals[k].y = __expf(vals[k].y - mx);
            vals[k].z = __expf(vals[k].z - mx); vals[k].w = __expf(vals[k].w - mx);
            sm += vals[k].x + vals[k].y + vals[k].z + vals[k].w;
        }
        sm = wsum16(sm);
        float inv = 1.0f / sm;
#pragma unroll
        for (int k = 0; k < 4; ++k) {
            vals[k].x *= inv; vals[k].y *= inv; vals[k].z *= inv; vals[k].w *= inv;
            *(float4*)&smF[rt * 256 + cb + k * 64] = vals[k];
        }
    }
    __syncthreads();
    // combine, elu, store
    {
        float invL[4];
#pragma unroll
        for (int r = 0; r < 4; ++r)
            invL[r] = 1.0f / *(const float*)(smem + RL_ + (g * 16 + lhi * 4 + r) * 4);
#pragma unroll
        for (int nt = 0; nt < 4; ++nt)
#pragma unroll
            for (int r = 0; r < 4; ++r) {
                int row = g * 16 + lhi * 4 + r;
                int f = h * 64 + nt * 16 + l15;
                float v = wacc[nt][r] * invL[r] + smF[row * 256 + f];
                out[(size_t)(i0 + row) * FOUT + f] = v > 0.f ? v : __expf(v) - 1.f;
            }
    }
}

extern "C" void kernel_launch(void* const* d_in, const int* in_sizes, int n_in,
                              void* d_out, int out_size, void* d_ws, size_t ws_size,
                              hipStream_t stream)
{
    const float* h      = (const float*)d_in[0];
    const int*   adj    = (const int*)d_in[1];
    const float* W      = (const float*)d_in[2];
    const float* Wl_w   = (const float*)d_in[3];
    const float* Wl_b   = (const float*)d_in[4];
    const float* Wqkv_w = (const float*)d_in[5];
    const float* Wqkv_b = (const float*)d_in[6];
    const float* a      = (const float*)d_in[7];
    float* out = (float*)d_out;

    float* ws = (float*)d_ws;
    float* T   = ws;                              // 1M floats
    float* Whb = ws + (1 << 20);                  // 1M floats
    unsigned short* u16b = (unsigned short*)(ws + (2 << 20));
    unsigned short* qh  = u16b;                   // 1M u16 each
    unsigned short* ql  = qh  + (1 << 20);
    unsigned short* kh  = ql  + (1 << 20);
    unsigned short* kl  = kh  + (1 << 20);
    unsigned short* vth = kl  + (1 << 20);
    unsigned short* wht = vth + (1 << 20);
    float* p1b = ws + (5 << 20);
    float* p2b = p1b + 4096;

    dim3 blk(256);
    gemm_f32<false, false, 0><<<dim3(4, 64), blk, 0, stream>>>(
        h, W, nullptr, T, nullptr, nullptr, nullptr, nullptr, nullptr, 4096, 256, 512);
    gemm_f32<true, true, 1><<<dim3(4, 64), blk, 0, stream>>>(
        T, Wl_w, Wl_b, Whb, wht, nullptr, nullptr, nullptr, nullptr, 4096, 256, 256);
    gemm_f32<true, true, 2><<<dim3(12, 64), blk, 0, stream>>>(
        Whb, Wqkv_w, Wqkv_b, nullptr, qh, ql, kh, kl, vth, 4096, 768, 256);
    compute_p<<<dim3(256), blk, 0, stream>>>(Whb, a, p1b, p2b);
    fused_attn<<<dim3(128), dim3(512), 0, stream>>>(
        qh, ql, kh, kl, vth, wht, p1b, p2b, adj, out);
}

// Round 4
// 289.603 us; speedup vs baseline: 9.4738x; 1.9066x over previous
//
#include <hip/hip_runtime.h>

typedef float  f32x4 __attribute__((ext_vector_type(4)));
typedef short  s16x8 __attribute__((ext_vector_type(8)));
typedef unsigned short u16x8 __attribute__((ext_vector_type(8)));

#define NROWS 4096
#define FOUT  256
#define ALPHA_LR 0.2f
#define SCALE 0.0625f
#define NEGV  -9.0e15f

static __device__ __forceinline__ unsigned short bf16_rne(float x) {
    unsigned u = __float_as_uint(x);
    u += 0x7fffu + ((u >> 16) & 1u);
    return (unsigned short)(u >> 16);
}
static __device__ __forceinline__ float bf2f(unsigned short h) {
    return __uint_as_float(((unsigned)h) << 16);
}
static __device__ __forceinline__ float wmax16(float v) {
#pragma unroll
    for (int o = 8; o; o >>= 1) v = fmaxf(v, __shfl_xor(v, o, 16));
    return v;
}
static __device__ __forceinline__ float wsum16(float v) {
#pragma unroll
    for (int o = 8; o; o >>= 1) v += __shfl_xor(v, o, 16);
    return v;
}
static __device__ __forceinline__ float wmax32(float v) {
#pragma unroll
    for (int o = 16; o; o >>= 1) v = fmaxf(v, __shfl_xor(v, o, 32));
    return v;
}
static __device__ __forceinline__ float wsum32(float v) {
#pragma unroll
    for (int o = 16; o; o >>= 1) v += __shfl_xor(v, o, 32);
    return v;
}

// ---------------------------------------------------------------------------
// fp32 GEMM with epilogue modes.
// EPI 0: C = v
// EPI 1: C = v AND o0[col*4096+row] = bf16(v)         (WhT)
// EPI 2: col<256 -> o0[row][col]=bf16 (q); col<512 -> o1[row][col-256] (k);
//        else o2[(col-512)*4096+row] (vT)
// ---------------------------------------------------------------------------
template <bool BT, bool BIAS, int EPI>
__global__ __launch_bounds__(256) void gemm_f32(
    const float* __restrict__ A, const float* __restrict__ B,
    const float* __restrict__ bias, float* __restrict__ C,
    unsigned short* __restrict__ o0, unsigned short* __restrict__ o1,
    unsigned short* __restrict__ o2,
    int M, int Nn, int K)
{
    __shared__ float As[16][68];
    __shared__ float Bs[16][68];

    const int tid = threadIdx.x;
    const int bm = blockIdx.y * 64;
    const int bn = blockIdx.x * 64;
    const int tx = tid & 15;
    const int ty = tid >> 4;

    float acc[4][4];
#pragma unroll
    for (int r = 0; r < 4; ++r)
#pragma unroll
        for (int c = 0; c < 4; ++c) acc[r][c] = 0.0f;

    for (int k0 = 0; k0 < K; k0 += 16) {
        __syncthreads();
        {
            const int r = tid >> 2;
            const int c4 = (tid & 3) * 4;
            float4 a4 = *(const float4*)&A[(size_t)(bm + r) * K + k0 + c4];
            As[c4 + 0][r] = a4.x; As[c4 + 1][r] = a4.y;
            As[c4 + 2][r] = a4.z; As[c4 + 3][r] = a4.w;
        }
        if (!BT) {
            const int r = tid >> 4;
            const int c4 = (tid & 15) * 4;
            *(float4*)&Bs[r][c4] = *(const float4*)&B[(size_t)(k0 + r) * Nn + bn + c4];
        } else {
            const int r = tid >> 2;
            const int c4 = (tid & 3) * 4;
            float4 b4 = *(const float4*)&B[(size_t)(bn + r) * K + k0 + c4];
            Bs[c4 + 0][r] = b4.x; Bs[c4 + 1][r] = b4.y;
            Bs[c4 + 2][r] = b4.z; Bs[c4 + 3][r] = b4.w;
        }
        __syncthreads();
#pragma unroll
        for (int kk = 0; kk < 16; ++kk) {
            float4 a4 = *(const float4*)&As[kk][ty * 4];
            float4 b4 = *(const float4*)&Bs[kk][tx * 4];
            acc[0][0] += a4.x * b4.x; acc[0][1] += a4.x * b4.y; acc[0][2] += a4.x * b4.z; acc[0][3] += a4.x * b4.w;
            acc[1][0] += a4.y * b4.x; acc[1][1] += a4.y * b4.y; acc[1][2] += a4.y * b4.z; acc[1][3] += a4.y * b4.w;
            acc[2][0] += a4.z * b4.x; acc[2][1] += a4.z * b4.y; acc[2][2] += a4.z * b4.z; acc[2][3] += a4.z * b4.w;
            acc[3][0] += a4.w * b4.x; acc[3][1] += a4.w * b4.y; acc[3][2] += a4.w * b4.z; acc[3][3] += a4.w * b4.w;
        }
    }

    float bv[4] = {0.f, 0.f, 0.f, 0.f};
    if (BIAS) {
#pragma unroll
        for (int c = 0; c < 4; ++c) bv[c] = bias[bn + tx * 4 + c];
    }

    if (EPI == 0) {
#pragma unroll
        for (int r = 0; r < 4; ++r) {
            float4 o;
            o.x = acc[r][0] + bv[0]; o.y = acc[r][1] + bv[1];
            o.z = acc[r][2] + bv[2]; o.w = acc[r][3] + bv[3];
            *(float4*)&C[(size_t)(bm + ty * 4 + r) * Nn + bn + tx * 4] = o;
        }
    } else {
#pragma unroll
        for (int r = 0; r < 4; ++r) {
            const int row = bm + ty * 4 + r;
#pragma unroll
            for (int c = 0; c < 4; ++c) {
                const int col = bn + tx * 4 + c;
                float v = acc[r][c] + bv[c];
                if (EPI == 1) {
                    C[(size_t)row * Nn + col] = v;
                    o0[(size_t)col * NROWS + row] = bf16_rne(v);
                } else {
                    if (col < 256)      o0[(size_t)row * 256 + col] = bf16_rne(v);
                    else if (col < 512) o1[(size_t)row * 256 + (col - 256)] = bf16_rne(v);
                    else                o2[(size_t)(col - 512) * NROWS + row] = bf16_rne(v);
                }
            }
        }
    }
}

// ---------------------------------------------------------------------------
// p1 = Wh @ a[:256], p2 = Wh @ a[256:]
// ---------------------------------------------------------------------------
__global__ __launch_bounds__(256) void compute_p(
    const float* __restrict__ Wh, const float* __restrict__ a,
    float* __restrict__ p1, float* __restrict__ p2)
{
    const int row = blockIdx.x * 16 + (threadIdx.x >> 4);
    const int c = threadIdx.x & 15;
    float s1 = 0.f, s2 = 0.f;
    for (int f = c; f < FOUT; f += 16) {
        float w = Wh[(size_t)row * FOUT + f];
        s1 += w * a[f];
        s2 += w * a[FOUT + f];
    }
    s1 = wsum16(s1);
    s2 = wsum16(s2);
    if (c == 0) { p1[row] = s1; p2[row] = s2; }
}

// ---------------------------------------------------------------------------
// Inner-attention stats, j-parallel. grid = 256 rowtiles x 8 chunks.
// 256 thr = 4 waves (one head each). Direct-from-global MFMA QK (bf16 hi).
// Writes per-chunk (m, z) partials.
// ---------------------------------------------------------------------------
__global__ __launch_bounds__(256) void stats_kernel(
    const unsigned short* __restrict__ qh_g, const unsigned short* __restrict__ kh_g,
    float* __restrict__ stats)
{
    const int tid = threadIdx.x;
    const int h = tid >> 6;
    const int ln = tid & 63;
    const int l15 = ln & 15;
    const int lhi = ln >> 4;
    const int rt = blockIdx.x >> 3;
    const int ch = blockIdx.x & 7;
    const int i0 = rt * 16;

    s16x8 qA[2];
#pragma unroll
    for (int ks = 0; ks < 2; ++ks)
        qA[ks] = *(const s16x8*)(qh_g + (size_t)(i0 + l15) * 256 + h * 64 + ks * 32 + lhi * 8);

    float m[4], z[4];
#pragma unroll
    for (int r = 0; r < 4; ++r) { m[r] = -3.0e38f; z[r] = 0.f; }

    for (int tt = 0; tt < 16; ++tt) {
        const int j0 = ch * 512 + tt * 32;
        f32x4 acc[2] = {{0.f,0.f,0.f,0.f},{0.f,0.f,0.f,0.f}};
#pragma unroll
        for (int ks = 0; ks < 2; ++ks)
#pragma unroll
            for (int nt = 0; nt < 2; ++nt) {
                s16x8 kB = *(const s16x8*)(kh_g + (size_t)(j0 + nt * 16 + l15) * 256 +
                                           h * 64 + ks * 32 + lhi * 8);
                acc[nt] = __builtin_amdgcn_mfma_f32_16x16x32_bf16(qA[ks], kB, acc[nt], 0, 0, 0);
            }
#pragma unroll
        for (int r = 0; r < 4; ++r) {
            float s0 = acc[0][r] * SCALE, s1 = acc[1][r] * SCALE;
            float mn = fmaxf(m[r], fmaxf(s0, s1));
            z[r] = z[r] * __expf(m[r] - mn) + __expf(s0 - mn) + __expf(s1 - mn);
            m[r] = mn;
        }
    }
#pragma unroll
    for (int r = 0; r < 4; ++r) {
        float mm = m[r], zz = z[r];
#pragma unroll
        for (int o = 1; o < 16; o <<= 1) {
            float mo = __shfl_xor(mm, o, 16);
            float zo = __shfl_xor(zz, o, 16);
            float mn = fmaxf(mm, mo);
            zz = zz * __expf(mm - mn) + zo * __expf(mo - mn);
            mm = mn;
        }
        if (l15 == 0) {
            size_t idx = (((size_t)(i0 + lhi * 4 + r) * 4 + h) * 8 + ch) * 2;
            stats[idx] = mm;
            stats[idx + 1] = zz;
        }
    }
}

// ---------------------------------------------------------------------------
// Main fused sweep, j-parallel x2. grid = 256 rowtiles x 2 chunks (512 blocks,
// 2/CU). 512 thr = 8 waves = (head h) x (j-half jg). 64 tiles of 32 j each.
// Emits per-chunk partial pacc/wacc (bf16) + (M, L).
// LDS: K 32x528, V/Wh 256x80, dots 4x16x80, ptil 16x80 -> 64832 B.
// ---------------------------------------------------------------------------
__global__ __launch_bounds__(512, 4) void main_attn(
    const unsigned short* __restrict__ qh_g, const unsigned short* __restrict__ kh_g,
    const unsigned short* __restrict__ vth_g, const unsigned short* __restrict__ wht_g,
    const float* __restrict__ stats, const float* __restrict__ p1g,
    const float* __restrict__ p2g, const int* __restrict__ adj,
    unsigned short* __restrict__ pacc_o, unsigned short* __restrict__ wacc_o,
    float* __restrict__ ml_o)
{
    enum { KT = 0, VT = 16896, WHT = 37376, DOTS = 57856, PTIL = 62976,
           ALP = 64256, MIZ = 64320, SMEMSZ = 64832 };
    __shared__ __align__(16) char smem[SMEMSZ];

    const int tid = threadIdx.x;
    const int w = tid >> 6;
    const int h = w & 3;
    const int jg = w >> 2;
    const int ln = tid & 63;
    const int l15 = ln & 15;
    const int lhi = ln >> 4;
    const int rt = blockIdx.x >> 1;
    const int ch = blockIdx.x & 1;
    const int i0 = rt * 16;
    const int jbase = ch * 2048;
    const int srow = tid >> 5;      // 0..15
    const int scol = tid & 31;      // 0..31

    // ---- merge inner-stats partials -> MIZ ----
    if (tid < 64) {
        int hh = tid >> 4, row = tid & 15;
        const float* sb = stats + ((size_t)(i0 + row) * 4 + hh) * 16;
        float M = -3.0e38f, Z = 0.f;
#pragma unroll
        for (int c = 0; c < 8; ++c) {
            float mc = sb[c * 2], zc = sb[c * 2 + 1];
            float mn = fmaxf(M, mc);
            Z = Z * __expf(M - mn) + zc * __expf(mc - mn);
            M = mn;
        }
        ((float*)(smem + MIZ))[(hh * 16 + row) * 2] = M;
        ((float*)(smem + MIZ))[(hh * 16 + row) * 2 + 1] = 1.0f / Z;
    }

    // ---- staging maps ----
    int laK[2], gK[2], laV[2], gV[2];
#pragma unroll
    for (int it = 0; it < 2; ++it) {
        int c = tid + it * 512;
        int kr = c >> 5, kc = c & 31;
        laK[it] = kr * 528 + kc * 16;
        gK[it] = kr * 256 + kc * 8;
        int vd = c >> 2, vc = c & 3;
        laV[it] = vd * 80 + vc * 16;
        gV[it] = vd * 4096 + vc * 8;
    }

    // ---- prologue staging of tile 0 ----
#pragma unroll
    for (int it = 0; it < 2; ++it) {
        *(uint4*)(smem + KT + laK[it])  = *(const uint4*)(kh_g  + (size_t)jbase * 256 + gK[it]);
        *(uint4*)(smem + VT + laV[it])  = *(const uint4*)(vth_g + (size_t)jbase + gV[it]);
        *(uint4*)(smem + WHT + laV[it]) = *(const uint4*)(wht_g + (size_t)jbase + gV[it]);
    }

    // persistent q fragments
    s16x8 qA[2];
#pragma unroll
    for (int ks = 0; ks < 2; ++ks)
        qA[ks] = *(const s16x8*)(qh_g + (size_t)(i0 + l15) * 256 + h * 64 + ks * 32 + lhi * 8);

    __syncthreads();

    float m_f[4], iz_f[4];
#pragma unroll
    for (int r = 0; r < 4; ++r) {
        m_f[r]  = ((float*)(smem + MIZ))[(h * 16 + lhi * 4 + r) * 2];
        iz_f[r] = ((float*)(smem + MIZ))[(h * 16 + lhi * 4 + r) * 2 + 1];
    }

    // fragment addresses
    int kaddr[2];
#pragma unroll
    for (int ks = 0; ks < 2; ++ks)
        kaddr[ks] = KT + (jg * 16 + l15) * 528 + h * 128 + ks * 64 + lhi * 16;
    const int daddr = DOTS + h * 1280 + l15 * 80 + lhi * 16;
    const int paddr = PTIL + l15 * 80 + lhi * 16;
    int vaddr[2], waddr[2];
#pragma unroll
    for (int nt = 0; nt < 2; ++nt) {
        int d = h * 64 + jg * 32 + nt * 16 + l15;
        vaddr[nt] = VT + d * 80 + lhi * 16;
        waddr[nt] = WHT + d * 80 + lhi * 16;
    }
    const int dwbase = DOTS + h * 1280 + jg * 32 + l15 * 2;

    f32x4 pacc[2] = {{0.f,0.f,0.f,0.f},{0.f,0.f,0.f,0.f}};
    f32x4 wacc[2] = {{0.f,0.f,0.f,0.f},{0.f,0.f,0.f,0.f}};
    float Mrun = -3.0e38f, Lrun = 0.0f;
    const float p1v = p1g[i0 + srow];

    int   adjc = adj[(size_t)(i0 + srow) * NROWS + jbase + scol];
    float p2c  = p2g[jbase + scol];

    for (int t = 0; t < 64; ++t) {
        const int jn = jbase + ((t + 1) & 63) * 32;
        // issue K(t+1)
        uint4 kr0 = *(const uint4*)(kh_g + (size_t)jn * 256 + gK[0]);
        uint4 kr1 = *(const uint4*)(kh_g + (size_t)jn * 256 + gK[1]);

        // ---- QK ----
        f32x4 qk = {0.f,0.f,0.f,0.f};
        __builtin_amdgcn_s_setprio(1);
        {
            s16x8 k0 = *(const s16x8*)(smem + kaddr[0]);
            s16x8 k1 = *(const s16x8*)(smem + kaddr[1]);
            qk = __builtin_amdgcn_mfma_f32_16x16x32_bf16(qA[0], k0, qk, 0, 0, 0);
            qk = __builtin_amdgcn_mfma_f32_16x16x32_bf16(qA[1], k1, qk, 0, 0, 0);
        }
        __builtin_amdgcn_s_setprio(0);
#pragma unroll
        for (int r = 0; r < 4; ++r) {
            float d = __expf(qk[r] * SCALE - m_f[r]) * iz_f[r];
            *(unsigned short*)(smem + dwbase + (lhi * 4 + r) * 80) = bf16_rne(d);
        }
        __syncthreads();  // B1: dots visible, K free, kr arrived

        // write K(t+1)
        *(uint4*)(smem + KT + laK[0]) = kr0;
        *(uint4*)(smem + KT + laK[1]) = kr1;
        // issue V/WH(t+1), adj/p2(t+1)
        uint4 vr0 = *(const uint4*)(vth_g + (size_t)jn + gV[0]);
        uint4 vr1 = *(const uint4*)(vth_g + (size_t)jn + gV[1]);
        uint4 wr0 = *(const uint4*)(wht_g + (size_t)jn + gV[0]);
        uint4 wr1 = *(const uint4*)(wht_g + (size_t)jn + gV[1]);
        int   adjn = adj[(size_t)(i0 + srow) * NROWS + jn + scol];
        float p2n  = p2g[jn + scol];

        // ---- PV ----
        __builtin_amdgcn_s_setprio(1);
        {
            s16x8 dA = *(const s16x8*)(smem + daddr);
            s16x8 v0 = *(const s16x8*)(smem + vaddr[0]);
            s16x8 v1 = *(const s16x8*)(smem + vaddr[1]);
            pacc[0] = __builtin_amdgcn_mfma_f32_16x16x32_bf16(dA, v0, pacc[0], 0, 0, 0);
            pacc[1] = __builtin_amdgcn_mfma_f32_16x16x32_bf16(dA, v1, pacc[1], 0, 0, 0);
        }
        __builtin_amdgcn_s_setprio(0);

        // ---- outer masked flash softmax ----
        {
            float ds = 0.f;
#pragma unroll
            for (int hh = 0; hh < 4; ++hh)
                ds += bf2f(*(const unsigned short*)(smem + DOTS + hh * 1280 + srow * 80 + scol * 2));
            float e = p1v + p2c; e = e > 0.f ? e : ALPHA_LR * e;
            float l = adjc > 0 ? e + ds : NEGV;
            float tm = wmax32(l);
            float Mn = fmaxf(Mrun, tm);
            float p = __expf(l - Mn);
            float ps = wsum32(p);
            float al = __expf(Mrun - Mn);
            Lrun = Lrun * al + ps;
            Mrun = Mn;
            if ((ln & 31) == 0) *(float*)(smem + ALP + srow * 4) = al;
            *(unsigned short*)(smem + PTIL + srow * 80 + scol * 2) = bf16_rne(p);
        }
        __syncthreads();  // B2: ptil/alpha visible, V free, vr/wr arrived

        // write V(t+1)
        *(uint4*)(smem + VT + laV[0]) = vr0;
        *(uint4*)(smem + VT + laV[1]) = vr1;

        // ---- A@Wh with flash rescale ----
        {
            float al_r[4];
#pragma unroll
            for (int r = 0; r < 4; ++r)
                al_r[r] = *(const float*)(smem + ALP + (lhi * 4 + r) * 4);
#pragma unroll
            for (int nt = 0; nt < 2; ++nt)
#pragma unroll
                for (int r = 0; r < 4; ++r) wacc[nt][r] *= al_r[r];
            s16x8 pA = *(const s16x8*)(smem + paddr);
            s16x8 w0 = *(const s16x8*)(smem + waddr[0]);
            s16x8 w1 = *(const s16x8*)(smem + waddr[1]);
            __builtin_amdgcn_s_setprio(1);
            wacc[0] = __builtin_amdgcn_mfma_f32_16x16x32_bf16(pA, w0, wacc[0], 0, 0, 0);
            wacc[1] = __builtin_amdgcn_mfma_f32_16x16x32_bf16(pA, w1, wacc[1], 0, 0, 0);
            __builtin_amdgcn_s_setprio(0);
        }
        __syncthreads();  // B3: WH free

        // write WH(t+1)
        *(uint4*)(smem + WHT + laV[0]) = wr0;
        *(uint4*)(smem + WHT + laV[1]) = wr1;

        adjc = adjn; p2c = p2n;
    }

    // ---- epilogue: partial outputs ----
    const size_t pbase = (size_t)(rt * 2 + ch) * 16 * 256;
#pragma unroll
    for (int nt = 0; nt < 2; ++nt)
#pragma unroll
        for (int r = 0; r < 4; ++r) {
            int row = lhi * 4 + r;
            int col = h * 64 + jg * 32 + nt * 16 + l15;
            pacc_o[pbase + row * 256 + col] = bf16_rne(pacc[nt][r]);
            wacc_o[pbase + row * 256 + col] = bf16_rne(wacc[nt][r]);
        }
    if ((ln & 31) == 0) {
        ml_o[((size_t)(rt * 2 + ch) * 16 + srow) * 2]     = Mrun;
        ml_o[((size_t)(rt * 2 + ch) * 16 + srow) * 2 + 1] = Lrun;
    }
}

// ---------------------------------------------------------------------------
// Merge: combine 2 j-chunks, Wh0 row softmax, elu, store.
// grid 256 (one rowtile), 256 thr: thread = (row, 16-col group).
// ---------------------------------------------------------------------------
__global__ __launch_bounds__(256) void merge_kernel(
    const unsigned short* __restrict__ pacc_b, const unsigned short* __restrict__ wacc_b,
    const float* __restrict__ ml, float* __restrict__ out)
{
    const int rt = blockIdx.x;
    const int tid = threadIdx.x;
    const int row = tid >> 4;
    const int cg = tid & 15;

    const size_t b0 = ((size_t)(rt * 2 + 0) * 16 + row) * 256 + cg * 16;
    const size_t b1 = ((size_t)(rt * 2 + 1) * 16 + row) * 256 + cg * 16;
    float M0 = ml[((size_t)(rt * 2 + 0) * 16 + row) * 2];
    float L0 = ml[((size_t)(rt * 2 + 0) * 16 + row) * 2 + 1];
    float M1 = ml[((size_t)(rt * 2 + 1) * 16 + row) * 2];
    float L1 = ml[((size_t)(rt * 2 + 1) * 16 + row) * 2 + 1];
    float M = fmaxf(M0, M1);
    float s0 = __expf(M0 - M), s1 = __expf(M1 - M);
    float invL = 1.0f / (L0 * s0 + L1 * s1);

    u16x8 pa[2][2], wa[2][2];
#pragma unroll
    for (int k = 0; k < 2; ++k) {
        pa[0][k] = *(const u16x8*)(pacc_b + b0 + k * 8);
        pa[1][k] = *(const u16x8*)(pacc_b + b1 + k * 8);
        wa[0][k] = *(const u16x8*)(wacc_b + b0 + k * 8);
        wa[1][k] = *(const u16x8*)(wacc_b + b1 + k * 8);
    }
    float p[16], wv[16];
    float mx = -3.0e38f;
#pragma unroll
    for (int k = 0; k < 16; ++k) {
        p[k] = bf2f(pa[0][k >> 3][k & 7]) + bf2f(pa[1][k >> 3][k & 7]);
        wv[k] = (bf2f(wa[0][k >> 3][k & 7]) * s0 + bf2f(wa[1][k >> 3][k & 7]) * s1) * invL;
        mx = fmaxf(mx, p[k]);
    }
    mx = wmax16(mx);
    float sm = 0.f;
#pragma unroll
    for (int k = 0; k < 16; ++k) { p[k] = __expf(p[k] - mx); sm += p[k]; }
    sm = wsum16(sm);
    float inv = 1.0f / sm;
    float* orow = out + ((size_t)(rt * 16 + row)) * 256 + cg * 16;
#pragma unroll
    for (int k4 = 0; k4 < 4; ++k4) {
        float4 o;
        float v;
        v = wv[k4*4+0] + p[k4*4+0] * inv; o.x = v > 0.f ? v : __expf(v) - 1.f;
        v = wv[k4*4+1] + p[k4*4+1] * inv; o.y = v > 0.f ? v : __expf(v) - 1.f;
        v = wv[k4*4+2] + p[k4*4+2] * inv; o.z = v > 0.f ? v : __expf(v) - 1.f;
        v = wv[k4*4+3] + p[k4*4+3] * inv; o.w = v > 0.f ? v : __expf(v) - 1.f;
        *(float4*)(orow + k4 * 4) = o;
    }
}

extern "C" void kernel_launch(void* const* d_in, const int* in_sizes, int n_in,
                              void* d_out, int out_size, void* d_ws, size_t ws_size,
                              hipStream_t stream)
{
    const float* h      = (const float*)d_in[0];
    const int*   adj    = (const int*)d_in[1];
    const float* W      = (const float*)d_in[2];
    const float* Wl_w   = (const float*)d_in[3];
    const float* Wl_b   = (const float*)d_in[4];
    const float* Wqkv_w = (const float*)d_in[5];
    const float* Wqkv_b = (const float*)d_in[6];
    const float* a      = (const float*)d_in[7];
    float* out = (float*)d_out;

    float* ws = (float*)d_ws;
    float* T   = ws;                                   // 1M f32 (later: pacc bf16)
    float* Whb = ws + (1 << 20);                       // 1M f32 (later: wacc bf16)
    unsigned short* qh  = (unsigned short*)(ws + (2 << 20));  // 1M u16 each
    unsigned short* kh  = qh + (1 << 20);
    unsigned short* vth = kh + (1 << 20);
    unsigned short* wht = vth + (1 << 20);
    float* p1b    = ws + (4 << 20);
    float* p2b    = p1b + 4096;
    float* statsb = p2b + 4096;                        // 4096*4*8*2 = 262144
    float* mlb    = statsb + 262144;                   // 512*16*2 = 16384
    unsigned short* pacc_b = (unsigned short*)T;
    unsigned short* wacc_b = (unsigned short*)Whb;

    dim3 blk(256);
    gemm_f32<false, false, 0><<<dim3(4, 64), blk, 0, stream>>>(
        h, W, nullptr, T, nullptr, nullptr, nullptr, 4096, 256, 512);
    gemm_f32<true, true, 1><<<dim3(4, 64), blk, 0, stream>>>(
        T, Wl_w, Wl_b, Whb, wht, nullptr, nullptr, 4096, 256, 256);
    gemm_f32<true, true, 2><<<dim3(12, 64), blk, 0, stream>>>(
        Whb, Wqkv_w, Wqkv_b, nullptr, qh, kh, vth, 4096, 768, 256);
    compute_p<<<dim3(256), blk, 0, stream>>>(Whb, a, p1b, p2b);
    stats_kernel<<<dim3(2048), blk, 0, stream>>>(qh, kh, statsb);
    main_attn<<<dim3(512), dim3(512), 0, stream>>>(
        qh, kh, vth, wht, statsb, p1b, p2b, adj, pacc_b, wacc_b, mlb);
    merge_kernel<<<dim3(256), blk, 0, stream>>>(pacc_b, wacc_b, mlb, out);
}